// Round 1
// baseline (755.016 us; speedup 1.0000x reference)
//
#include <hip/hip_runtime.h>
#include <hip/hip_bf16.h>

// Problem constants
// BS=64 NQ=900 L=1024 D=768 H=256 E=8 TOPK=2 MOE_W=0.5
// out: (64,900,1024) f32

typedef __attribute__((ext_vector_type(8))) short bf16x8;
typedef __attribute__((ext_vector_type(4))) float f32x4;

__device__ __forceinline__ unsigned short f2bf(float f) {
    unsigned u = __builtin_bit_cast(unsigned, f);
    u += 0x7fffu + ((u >> 16) & 1u);   // RNE; inputs finite
    return (unsigned short)(u >> 16);
}
__device__ __forceinline__ float bf2f(unsigned short h) {
    unsigned u = ((unsigned)h) << 16;
    return __builtin_bit_cast(float, u);
}
__device__ __forceinline__ void gload16(const void* g, void* l) {
    __builtin_amdgcn_global_load_lds(
        (const __attribute__((address_space(1))) void*)g,
        (__attribute__((address_space(3))) void*)l, 16, 0, 0);
}

// ---------------------------------------------------------------- prep:
// cast x -> bf16; build WcatT[n=j*256+h][d] (bf16, K-contiguous rows) and bcat[2304]
__global__ __launch_bounds__(256) void k0_prep(
    const float* __restrict__ x, const float* __restrict__ proj_w,
    const float* __restrict__ proj_b, const float* __restrict__ expert_w,
    const float* __restrict__ expert_b, unsigned short* __restrict__ x_bf,
    unsigned short* __restrict__ wcatT, float* __restrict__ bcat)
{
    int idx = blockIdx.x * 256 + threadIdx.x;
    if (idx < 64 * 900 * 256) x_bf[idx] = f2bf(x[idx]);
    if (idx < 2304 * 768) {
        int n = idx / 768, d = idx - n * 768;
        int j = n >> 8, h = n & 255;
        float v = (j < 8) ? expert_w[((size_t)j * 768 + d) * 256 + h]
                          : proj_w[(size_t)d * 256 + h];
        wcatT[(size_t)n * 768 + d] = f2bf(v);
    }
    if (idx < 2304) {
        int j = idx >> 8, h = idx & 255;
        bcat[idx] = (j < 8) ? expert_b[j * 256 + h] : proj_b[h];
    }
}

// ---------------------------------------------------------------- K1:
// per token row: normalize(768), write emb bf16; gate logits(8) f32, softmax,
// top-2 -> coef[16] (coef[e]=0.5*p_e for top2, coef[8]=0.5); token_bias.
__global__ __launch_bounds__(256) void k1_gate(
    const float* __restrict__ emb_in, const float* __restrict__ gate_w,
    const float* __restrict__ gate_b, const float* __restrict__ bias_lang,
    const float* __restrict__ bias0, unsigned short* __restrict__ emb_bf,
    float* __restrict__ coef, float* __restrict__ tbias)
{
    int r = blockIdx.x;
    int tid = threadIdx.x, lane = tid & 63, w = tid >> 6;
    const float* row = emb_in + (size_t)r * 768;
    float v0 = row[tid], v1 = row[tid + 256], v2 = row[tid + 512];
    float ss = v0 * v0 + v1 * v1 + v2 * v2;
    #pragma unroll
    for (int off = 32; off; off >>= 1) ss += __shfl_down(ss, off, 64);
    __shared__ float sred[4];
    __shared__ float srn;
    if (lane == 0) sred[w] = ss;
    __syncthreads();
    if (tid == 0) srn = rsqrtf(sred[0] + sred[1] + sred[2] + sred[3]);
    __syncthreads();
    float rn = srn;
    float e0 = v0 * rn, e1 = v1 * rn, e2 = v2 * rn;
    emb_bf[(size_t)r * 768 + tid]       = f2bf(e0);
    emb_bf[(size_t)r * 768 + tid + 256] = f2bf(e1);
    emb_bf[(size_t)r * 768 + tid + 512] = f2bf(e2);

    float red[9];
    #pragma unroll
    for (int i = 0; i < 9; i++) red[i] = 0.f;
    float ev[3] = {e0, e1, e2};
    #pragma unroll
    for (int k = 0; k < 3; k++) {
        int d = tid + 256 * k;
        float ed = ev[k];
        #pragma unroll
        for (int e = 0; e < 8; e++) red[e] += ed * gate_w[d * 8 + e];
        red[8] += ed * bias_lang[d];
    }
    #pragma unroll
    for (int off = 32; off; off >>= 1) {
        #pragma unroll
        for (int i = 0; i < 9; i++) red[i] += __shfl_down(red[i], off, 64);
    }
    __shared__ float sg[4][9];
    if (lane == 0) {
        #pragma unroll
        for (int i = 0; i < 9; i++) sg[w][i] = red[i];
    }
    __syncthreads();
    if (tid == 0) {
        float g[8];
        #pragma unroll
        for (int e = 0; e < 8; e++)
            g[e] = sg[0][e] + sg[1][e] + sg[2][e] + sg[3][e] + gate_b[e];
        float tb = sg[0][8] + sg[1][8] + sg[2][8] + sg[3][8] + bias0[0];
        float m = g[0];
        #pragma unroll
        for (int e = 1; e < 8; e++) m = fmaxf(m, g[e]);
        float p[8], s = 0.f;
        #pragma unroll
        for (int e = 0; e < 8; e++) { p[e] = __expf(g[e] - m); s += p[e]; }
        float inv = 1.f / s;
        int i1 = 0;
        #pragma unroll
        for (int e = 1; e < 8; e++) if (g[e] > g[i1]) i1 = e;
        int i2 = (i1 == 0) ? 1 : 0;
        #pragma unroll
        for (int e = 0; e < 8; e++) if (e != i1 && g[e] > g[i2]) i2 = e;
        float cc[9];
        #pragma unroll
        for (int j = 0; j < 9; j++) cc[j] = 0.f;
        cc[i1] = 0.5f * p[i1] * inv;
        cc[i2] = 0.5f * p[i2] * inv;
        cc[8]  = 0.5f;
        #pragma unroll
        for (int j = 0; j < 9; j++) coef[(size_t)r * 16 + j] = cc[j];
        tbias[r] = tb;
    }
}

// ---------------------------------------------------------------- K2:
// tokens[r][h] = sum_j coef_j[r] * (emb[r] @ W_j + b_j)[h], bf16 out.
// Block: 64 rows x 256 cols (full H), 4 waves side-by-side in N (64x64 each).
// j-outer: per-j partial accumulator over full K, then coef-scaled into final.
__global__ __launch_bounds__(256, 2) void k2_tokens(
    const unsigned short* __restrict__ emb_bf, const unsigned short* __restrict__ wcatT,
    const float* __restrict__ bcat, const float* __restrict__ coef,
    unsigned short* __restrict__ tokens)
{
    int tid = threadIdx.x, lane = tid & 63, w = tid >> 6;
    int rowBase = blockIdx.x * 64;
    __shared__ __align__(16) unsigned short As[64 * 32];    // 4KB
    __shared__ __align__(16) unsigned short Bs[256 * 32];   // 16KB
    __shared__ float cS[9][64];
    for (int i = tid; i < 9 * 64; i += 256) {
        int j = i >> 6, rr = i & 63;
        cS[j][rr] = coef[(size_t)(rowBase + rr) * 16 + j];
    }
    f32x4 fin[4][4];
    #pragma unroll
    for (int mi = 0; mi < 4; mi++)
        #pragma unroll
        for (int ni = 0; ni < 4; ni++) fin[mi][ni] = f32x4{0.f, 0.f, 0.f, 0.f};
    int wn = w;
    int arow = w * 16 + (lane >> 2);     // staging row within tile
    int acol = (lane & 3) * 8;           // staging col (bf16 elems)
    int r16 = lane & 15, r4 = lane >> 4;

    #pragma unroll 1
    for (int j = 0; j < 9; j++) {
        f32x4 accp[4][4];
        #pragma unroll
        for (int mi = 0; mi < 4; mi++)
            #pragma unroll
            for (int ni = 0; ni < 4; ni++) accp[mi][ni] = f32x4{0.f, 0.f, 0.f, 0.f};
        for (int kt = 0; kt < 24; kt++) {
            __syncthreads();
            gload16(&emb_bf[(size_t)(rowBase + arow) * 768 + kt * 32 + acol], &As[w * 512]);
            #pragma unroll
            for (int i = 0; i < 4; i++) {
                int rb = w * 4 + i;
                int n = rb * 16 + (lane >> 2);
                gload16(&wcatT[(size_t)(j * 256 + n) * 768 + kt * 32 + acol], &Bs[rb * 512]);
            }
            __syncthreads();
            bf16x8 a[4], b[4];
            #pragma unroll
            for (int mi = 0; mi < 4; mi++)
                a[mi] = *(const bf16x8*)&As[(mi * 16 + r16) * 32 + r4 * 8];
            #pragma unroll
            for (int ni = 0; ni < 4; ni++)
                b[ni] = *(const bf16x8*)&Bs[(wn * 64 + ni * 16 + r16) * 32 + r4 * 8];
            #pragma unroll
            for (int mi = 0; mi < 4; mi++)
                #pragma unroll
                for (int ni = 0; ni < 4; ni++)
                    accp[mi][ni] = __builtin_amdgcn_mfma_f32_16x16x32_bf16(
                        a[mi], b[ni], accp[mi][ni], 0, 0, 0);
        }
        float bj[4];
        #pragma unroll
        for (int ni = 0; ni < 4; ni++) bj[ni] = bcat[j * 256 + wn * 64 + ni * 16 + r16];
        #pragma unroll
        for (int mi = 0; mi < 4; mi++) {
            float cr[4];
            #pragma unroll
            for (int e = 0; e < 4; e++) cr[e] = cS[j][mi * 16 + r4 * 4 + e];
            #pragma unroll
            for (int ni = 0; ni < 4; ni++)
                #pragma unroll
                for (int e = 0; e < 4; e++)
                    fin[mi][ni][e] += cr[e] * (accp[mi][ni][e] + bj[ni]);
        }
    }
    #pragma unroll
    for (int mi = 0; mi < 4; mi++)
        #pragma unroll
        for (int ni = 0; ni < 4; ni++)
            #pragma unroll
            for (int e = 0; e < 4; e++) {
                int rrow = rowBase + mi * 16 + r4 * 4 + e;
                int col = wn * 64 + ni * 16 + r16;
                tokens[(size_t)rrow * 256 + col] = f2bf(fin[mi][ni][e]);
            }
}

// ---------------------------------------------------------------- K3:
// logit[b][q][l] = clip(x[b,q]·tokens[b,l] * exp(-log_scale) + tbias[b,l])
// Per-batch GEMM M=900 N=1024 K=256; tile 128x128, 4 waves 2x2 (64x64 each).
__global__ __launch_bounds__(256, 2) void k3_logit(
    const unsigned short* __restrict__ x_bf, const unsigned short* __restrict__ tokens,
    const float* __restrict__ tbias, const float* __restrict__ log_scale,
    float* __restrict__ out)
{
    int tid = threadIdx.x, lane = tid & 63, w = tid >> 6;
    int wm = w >> 1, wn = w & 1;
    int tn = blockIdx.x, tm = blockIdx.y, b = blockIdx.z;
    __shared__ __align__(16) unsigned short As[128 * 32];   // 8KB
    __shared__ __align__(16) unsigned short Bs[128 * 32];   // 8KB
    const unsigned short* A = x_bf + (size_t)b * 900 * 256;
    const unsigned short* B = tokens + (size_t)b * 1024 * 256;
    f32x4 acc[4][4];
    #pragma unroll
    for (int mi = 0; mi < 4; mi++)
        #pragma unroll
        for (int ni = 0; ni < 4; ni++) acc[mi][ni] = f32x4{0.f, 0.f, 0.f, 0.f};
    int r16 = lane & 15, r4 = lane >> 4;
    int srow = lane >> 2, scol = (lane & 3) * 8;
    for (int kt = 0; kt < 8; kt++) {
        __syncthreads();
        #pragma unroll
        for (int i = 0; i < 2; i++) {
            int rb = w * 2 + i;
            int ar = tm * 128 + rb * 16 + srow;
            if (ar > 899) ar = 899;              // clamp (stores guarded)
            gload16(&A[(size_t)ar * 256 + kt * 32 + scol], &As[rb * 512]);
            int nr = tn * 128 + rb * 16 + srow;
            gload16(&B[(size_t)nr * 256 + kt * 32 + scol], &Bs[rb * 512]);
        }
        __syncthreads();
        bf16x8 a[4], bb[4];
        #pragma unroll
        for (int mi = 0; mi < 4; mi++)
            a[mi] = *(const bf16x8*)&As[(wm * 64 + mi * 16 + r16) * 32 + r4 * 8];
        #pragma unroll
        for (int ni = 0; ni < 4; ni++)
            bb[ni] = *(const bf16x8*)&Bs[(wn * 64 + ni * 16 + r16) * 32 + r4 * 8];
        #pragma unroll
        for (int mi = 0; mi < 4; mi++)
            #pragma unroll
            for (int ni = 0; ni < 4; ni++)
                acc[mi][ni] = __builtin_amdgcn_mfma_f32_16x16x32_bf16(
                    a[mi], bb[ni], acc[mi][ni], 0, 0, 0);
    }
    float inv = __expf(-log_scale[0]);
    #pragma unroll
    for (int ni = 0; ni < 4; ni++) {
        int l = tn * 128 + wn * 64 + ni * 16 + r16;
        float tbv = tbias[b * 1024 + l];
        #pragma unroll
        for (int mi = 0; mi < 4; mi++) {
            #pragma unroll
            for (int e = 0; e < 4; e++) {
                int q = tm * 128 + wm * 64 + mi * 16 + r4 * 4 + e;
                if (q < 900) {
                    float vv = acc[mi][ni][e] * inv + tbv;
                    vv = fminf(fmaxf(vv, -50000.f), 50000.f);
                    out[((size_t)b * 900 + q) * 1024 + l] = vv;
                }
            }
        }
    }
}

// ----------------------------------------------------------------
extern "C" void kernel_launch(void* const* d_in, const int* in_sizes, int n_in,
                              void* d_out, int out_size, void* d_ws, size_t ws_size,
                              hipStream_t stream)
{
    const float* x         = (const float*)d_in[0];
    const float* embedding = (const float*)d_in[1];
    const float* proj_w    = (const float*)d_in[2];
    const float* proj_b    = (const float*)d_in[3];
    const float* gate_w    = (const float*)d_in[4];
    const float* gate_b    = (const float*)d_in[5];
    const float* expert_w  = (const float*)d_in[6];
    const float* expert_b  = (const float*)d_in[7];
    const float* bias_lang = (const float*)d_in[8];
    const float* bias0     = (const float*)d_in[9];
    const float* log_scale = (const float*)d_in[10];
    float* out = (float*)d_out;

    size_t off = 0;
    char* base = (char*)d_ws;
    auto alloc = [&](size_t bytes) -> void* {
        void* p = base + off;
        off += (bytes + 255) & ~(size_t)255;
        return p;
    };
    unsigned short* emb_bf = (unsigned short*)alloc((size_t)65536 * 768 * 2); // 96MB
    unsigned short* x_bf   = (unsigned short*)alloc((size_t)14745600 * 2);    // 28MB
    unsigned short* wcatT  = (unsigned short*)alloc((size_t)2304 * 768 * 2);  // 3.4MB
    float* bcat            = (float*)alloc(2304 * 4);
    float* coef            = (float*)alloc((size_t)65536 * 16 * 4);           // 4MB
    float* tbias           = (float*)alloc((size_t)65536 * 4);
    unsigned short* tokens = (unsigned short*)alloc((size_t)65536 * 256 * 2); // 32MB

    k0_prep<<<57600, 256, 0, stream>>>(x, proj_w, proj_b, expert_w, expert_b,
                                       x_bf, wcatT, bcat);
    k1_gate<<<65536, 256, 0, stream>>>(embedding, gate_w, gate_b, bias_lang, bias0,
                                       emb_bf, coef, tbias);
    k2_tokens<<<1024, 256, 0, stream>>>(emb_bf, wcatT, bcat, coef, tokens);
    dim3 g3(8, 8, 64);
    k3_logit<<<g3, 256, 0, stream>>>(x_bf, tokens, tbias, log_scale, out);
}

// Round 2
// 713.613 us; speedup vs baseline: 1.0580x; 1.0580x over previous
//
#include <hip/hip_runtime.h>
#include <hip/hip_bf16.h>

// BS=64 NQ=900 L=1024 D=768 H=256 E=8 TOPK=2 MOE_W=0.5
// out: (64,900,1024) f32

typedef __attribute__((ext_vector_type(8))) short bf16x8;
typedef __attribute__((ext_vector_type(4))) float f32x4;

__device__ __forceinline__ unsigned short f2bf(float f) {
    unsigned u = __builtin_bit_cast(unsigned, f);
    u += 0x7fffu + ((u >> 16) & 1u);   // RNE; inputs finite
    return (unsigned short)(u >> 16);
}
__device__ __forceinline__ float bf2f(unsigned short h) {
    unsigned u = ((unsigned)h) << 16;
    return __builtin_bit_cast(float, u);
}
__device__ __forceinline__ void gload16(const void* g, void* l) {
    __builtin_amdgcn_global_load_lds(
        (const __attribute__((address_space(1))) void*)g,
        (__attribute__((address_space(3))) void*)l, 16, 0, 0);
}
// pack two f32 -> one u32 of 2 bf16 (RNE), lo = a, hi = b
__device__ __forceinline__ unsigned cvt_pk_bf16(float a, float b) {
    unsigned r;
    asm("v_cvt_pk_bf16_f32 %0, %1, %2" : "=v"(r) : "v"(a), "v"(b));
    return r;
}

// ---------------------------------------------------------------- prep:
__global__ __launch_bounds__(256) void k0_prep(
    const float* __restrict__ x, const float* __restrict__ proj_w,
    const float* __restrict__ proj_b, const float* __restrict__ expert_w,
    const float* __restrict__ expert_b, unsigned short* __restrict__ x_bf,
    unsigned short* __restrict__ wcatT, float* __restrict__ bcat)
{
    int idx = blockIdx.x * 256 + threadIdx.x;
    if (idx < 64 * 900 * 256) x_bf[idx] = f2bf(x[idx]);
    if (idx < 2304 * 768) {
        int n = idx / 768, d = idx - n * 768;
        int j = n >> 8, h = n & 255;
        float v = (j < 8) ? expert_w[((size_t)j * 768 + d) * 256 + h]
                          : proj_w[(size_t)d * 256 + h];
        wcatT[(size_t)n * 768 + d] = f2bf(v);
    }
    if (idx < 2304) {
        int j = idx >> 8, h = idx & 255;
        bcat[idx] = (j < 8) ? expert_b[j * 256 + h] : proj_b[h];
    }
}

// ---------------------------------------------------------------- K1 (unchanged):
__global__ __launch_bounds__(256) void k1_gate(
    const float* __restrict__ emb_in, const float* __restrict__ gate_w,
    const float* __restrict__ gate_b, const float* __restrict__ bias_lang,
    const float* __restrict__ bias0, unsigned short* __restrict__ emb_bf,
    float* __restrict__ coef, float* __restrict__ tbias)
{
    int r = blockIdx.x;
    int tid = threadIdx.x, lane = tid & 63, w = tid >> 6;
    const float* row = emb_in + (size_t)r * 768;
    float v0 = row[tid], v1 = row[tid + 256], v2 = row[tid + 512];
    float ss = v0 * v0 + v1 * v1 + v2 * v2;
    #pragma unroll
    for (int off = 32; off; off >>= 1) ss += __shfl_down(ss, off, 64);
    __shared__ float sred[4];
    __shared__ float srn;
    if (lane == 0) sred[w] = ss;
    __syncthreads();
    if (tid == 0) srn = rsqrtf(sred[0] + sred[1] + sred[2] + sred[3]);
    __syncthreads();
    float rn = srn;
    float e0 = v0 * rn, e1 = v1 * rn, e2 = v2 * rn;
    emb_bf[(size_t)r * 768 + tid]       = f2bf(e0);
    emb_bf[(size_t)r * 768 + tid + 256] = f2bf(e1);
    emb_bf[(size_t)r * 768 + tid + 512] = f2bf(e2);

    float red[9];
    #pragma unroll
    for (int i = 0; i < 9; i++) red[i] = 0.f;
    float ev[3] = {e0, e1, e2};
    #pragma unroll
    for (int k = 0; k < 3; k++) {
        int d = tid + 256 * k;
        float ed = ev[k];
        #pragma unroll
        for (int e = 0; e < 8; e++) red[e] += ed * gate_w[d * 8 + e];
        red[8] += ed * bias_lang[d];
    }
    #pragma unroll
    for (int off = 32; off; off >>= 1) {
        #pragma unroll
        for (int i = 0; i < 9; i++) red[i] += __shfl_down(red[i], off, 64);
    }
    __shared__ float sg[4][9];
    if (lane == 0) {
        #pragma unroll
        for (int i = 0; i < 9; i++) sg[w][i] = red[i];
    }
    __syncthreads();
    if (tid == 0) {
        float g[8];
        #pragma unroll
        for (int e = 0; e < 8; e++)
            g[e] = sg[0][e] + sg[1][e] + sg[2][e] + sg[3][e] + gate_b[e];
        float tb = sg[0][8] + sg[1][8] + sg[2][8] + sg[3][8] + bias0[0];
        float m = g[0];
        #pragma unroll
        for (int e = 1; e < 8; e++) m = fmaxf(m, g[e]);
        float p[8], s = 0.f;
        #pragma unroll
        for (int e = 0; e < 8; e++) { p[e] = __expf(g[e] - m); s += p[e]; }
        float inv = 1.f / s;
        int i1 = 0;
        #pragma unroll
        for (int e = 1; e < 8; e++) if (g[e] > g[i1]) i1 = e;
        int i2 = (i1 == 0) ? 1 : 0;
        #pragma unroll
        for (int e = 0; e < 8; e++) if (e != i1 && g[e] > g[i2]) i2 = e;
        float cc[9];
        #pragma unroll
        for (int j = 0; j < 9; j++) cc[j] = 0.f;
        cc[i1] = 0.5f * p[i1] * inv;
        cc[i2] = 0.5f * p[i2] * inv;
        cc[8]  = 0.5f;
        #pragma unroll
        for (int j = 0; j < 9; j++) coef[(size_t)r * 16 + j] = cc[j];
        tbias[r] = tb;
    }
}

// ---------------------------------------------------------------- K2:
// Single-chain GEMM: acc += (c_j[row] * emb[row]) @ W_j  for j=0..8, k=0..767.
// BM=128, BN=256 (full H), BK=32, 8 waves (2M x 4N), 2-phase dbuf, 1 barrier/iter.
// A staged once per kt (j-inner reuses LDS-resident A, unpacked once to f32 regs).
// LDS seg-swizzle: 16B seg index ^= (row&3), pre-swizzled on the GLOBAL source
// (global_load_lds writes linearly), un-swizzled on the ds_read side.
__global__ __launch_bounds__(512, 2) void k2_tokens(
    const unsigned short* __restrict__ emb_bf, const unsigned short* __restrict__ wcatT,
    const float* __restrict__ bcat, const float* __restrict__ coef,
    unsigned short* __restrict__ tokens)
{
    int tid = threadIdx.x, lane = tid & 63, w = tid >> 6;
    int wm = w >> 2, wn = w & 3;                 // 2 x 4 wave grid, 64x64 each
    int rowBase = blockIdx.x * 128;
    __shared__ __align__(16) unsigned short As[2][128 * 32];   // 2 x 8KB
    __shared__ __align__(16) unsigned short Bs[2][256 * 32];   // 2 x 16KB
    __shared__ float cS[9][128];
    for (int i = tid; i < 9 * 128; i += 512) {
        int j = i >> 7, rr = i & 127;
        cS[j][rr] = coef[(size_t)(rowBase + rr) * 16 + j];
    }
    int r16 = lane & 15, r4 = lane >> 4;
    int srowA = tid >> 2, ssegA = (tid & 3) ^ (srowA & 3);     // swizzled source seg

    auto stageA = [&](int kt, int buf) {
        gload16(&emb_bf[(size_t)(rowBase + srowA) * 768 + kt * 32 + ssegA * 8],
                &As[buf][w * 512]);               // wave-uniform LDS base
    };
    auto stageB = [&](int kt, int j, int buf) {
        #pragma unroll
        for (int i = 0; i < 2; i++) {
            int u = i * 512 + tid;
            int row = u >> 2, seg = (u & 3) ^ (row & 3);
            gload16(&wcatT[(size_t)(j * 256 + row) * 768 + kt * 32 + seg * 8],
                    &Bs[buf][i * 4096 + w * 512]);
        }
    };

    f32x4 acc[4][4];
    #pragma unroll
    for (int mi = 0; mi < 4; mi++)
        #pragma unroll
        for (int ni = 0; ni < 4; ni++) acc[mi][ni] = f32x4{0.f, 0.f, 0.f, 0.f};

    stageA(0, 0);
    stageB(0, 0, 0);
    __syncthreads();

    int bufA = 0, bufB = 0;
    #pragma unroll 1
    for (int kt = 0; kt < 24; ++kt) {
        // read + unpack this kt's A fragments once (reused across all 9 j)
        float af[4][8];
        #pragma unroll
        for (int mi = 0; mi < 4; mi++) {
            int row = wm * 64 + mi * 16 + r16;
            bf16x8 a = *(const bf16x8*)&As[bufA][row * 32 + (r4 ^ (row & 3)) * 8];
            #pragma unroll
            for (int e = 0; e < 8; e++) af[mi][e] = bf2f((unsigned short)a[e]);
        }
        #pragma unroll
        for (int j = 0; j < 9; ++j) {
            // prefetch next tile(s) into the other buffers
            if (j == 8 && kt < 23) stageA(kt + 1, bufA ^ 1);
            if (!(kt == 23 && j == 8)) {
                int nkt = (j == 8) ? kt + 1 : kt;
                int nj  = (j == 8) ? 0 : j + 1;
                stageB(nkt, nj, bufB ^ 1);
            }
            // B fragments (swizzled read)
            bf16x8 b[4];
            #pragma unroll
            for (int ni = 0; ni < 4; ni++) {
                int row = wn * 64 + ni * 16 + r16;
                b[ni] = *(const bf16x8*)&Bs[bufB][row * 32 + (r4 ^ (row & 3)) * 8];
            }
            // per-lane coef scale of A (A-frag row = lane&15), repack to bf16
            bf16x8 as_[4];
            #pragma unroll
            for (int mi = 0; mi < 4; mi++) {
                float c = cS[j][wm * 64 + mi * 16 + r16];
                union { bf16x8 v; unsigned u[4]; } pk;
                #pragma unroll
                for (int p = 0; p < 4; p++)
                    pk.u[p] = cvt_pk_bf16(af[mi][2 * p] * c, af[mi][2 * p + 1] * c);
                as_[mi] = pk.v;
            }
            #pragma unroll
            for (int mi = 0; mi < 4; mi++)
                #pragma unroll
                for (int ni = 0; ni < 4; ni++)
                    acc[mi][ni] = __builtin_amdgcn_mfma_f32_16x16x32_bf16(
                        as_[mi], b[ni], acc[mi][ni], 0, 0, 0);
            __syncthreads();                      // drains vmcnt too
            bufB ^= 1;
        }
        bufA ^= 1;
    }

    // epilogue: bias = sum_j c_j[row] * b_j[col]; write bf16 tokens
    float bj[9][4];
    #pragma unroll
    for (int j = 0; j < 9; j++)
        #pragma unroll
        for (int ni = 0; ni < 4; ni++)
            bj[j][ni] = bcat[j * 256 + wn * 64 + ni * 16 + r16];
    #pragma unroll
    for (int mi = 0; mi < 4; mi++) {
        #pragma unroll
        for (int e = 0; e < 4; e++) {
            int rloc = wm * 64 + mi * 16 + r4 * 4 + e;
            float cj[9];
            #pragma unroll
            for (int j = 0; j < 9; j++) cj[j] = cS[j][rloc];
            #pragma unroll
            for (int ni = 0; ni < 4; ni++) {
                float bias = 0.f;
                #pragma unroll
                for (int j = 0; j < 9; j++) bias += cj[j] * bj[j][ni];
                int col = wn * 64 + ni * 16 + r16;
                tokens[(size_t)(rowBase + rloc) * 256 + col] =
                    f2bf(acc[mi][ni][e] + bias);
            }
        }
    }
}

// ---------------------------------------------------------------- K3:
// logit[b][q][l] = clip(x[b,q]·tokens[b,l] * exp(-log_scale) + tbias[b,l])
// Per-batch GEMM M=900 N=1024 K=256; tile 128x128, 4 waves 2x2; 2-phase dbuf.
__global__ __launch_bounds__(256, 3) void k3_logit(
    const unsigned short* __restrict__ x_bf, const unsigned short* __restrict__ tokens,
    const float* __restrict__ tbias, const float* __restrict__ log_scale,
    float* __restrict__ out)
{
    int tid = threadIdx.x, lane = tid & 63, w = tid >> 6;
    int wm = w >> 1, wn = w & 1;
    int tn = blockIdx.x, tm = blockIdx.y, b = blockIdx.z;
    __shared__ __align__(16) unsigned short As[2][128 * 32];   // 2 x 8KB
    __shared__ __align__(16) unsigned short Bs[2][128 * 32];   // 2 x 8KB
    const unsigned short* A = x_bf + (size_t)b * 900 * 256;
    const unsigned short* B = tokens + (size_t)b * 1024 * 256;
    f32x4 acc[4][4];
    #pragma unroll
    for (int mi = 0; mi < 4; mi++)
        #pragma unroll
        for (int ni = 0; ni < 4; ni++) acc[mi][ni] = f32x4{0.f, 0.f, 0.f, 0.f};
    int r16 = lane & 15, r4 = lane >> 4;

    auto stage = [&](int kt, int buf) {
        #pragma unroll
        for (int i = 0; i < 2; i++) {
            int u = i * 256 + tid;
            int row = u >> 2, seg = (u & 3) ^ (row & 3);
            int ar = tm * 128 + row;
            if (ar > 899) ar = 899;              // clamp (stores guarded)
            gload16(&A[(size_t)ar * 256 + kt * 32 + seg * 8],
                    &As[buf][i * 2048 + w * 512]);
            int nr = tn * 128 + row;
            gload16(&B[(size_t)nr * 256 + kt * 32 + seg * 8],
                    &Bs[buf][i * 2048 + w * 512]);
        }
    };

    stage(0, 0);
    __syncthreads();
    int buf = 0;
    #pragma unroll 1
    for (int kt = 0; kt < 8; ++kt) {
        if (kt < 7) stage(kt + 1, buf ^ 1);
        bf16x8 a[4], bb[4];
        #pragma unroll
        for (int mi = 0; mi < 4; mi++) {
            int row = wm * 64 + mi * 16 + r16;
            a[mi] = *(const bf16x8*)&As[buf][row * 32 + (r4 ^ (row & 3)) * 8];
        }
        #pragma unroll
        for (int ni = 0; ni < 4; ni++) {
            int row = wn * 64 + ni * 16 + r16;
            bb[ni] = *(const bf16x8*)&Bs[buf][row * 32 + (r4 ^ (row & 3)) * 8];
        }
        #pragma unroll
        for (int mi = 0; mi < 4; mi++)
            #pragma unroll
            for (int ni = 0; ni < 4; ni++)
                acc[mi][ni] = __builtin_amdgcn_mfma_f32_16x16x32_bf16(
                    a[mi], bb[ni], acc[mi][ni], 0, 0, 0);
        __syncthreads();
        buf ^= 1;
    }
    float inv = __expf(-log_scale[0]);
    #pragma unroll
    for (int ni = 0; ni < 4; ni++) {
        int l = tn * 128 + wn * 64 + ni * 16 + r16;
        float tbv = tbias[b * 1024 + l];
        #pragma unroll
        for (int mi = 0; mi < 4; mi++) {
            #pragma unroll
            for (int e = 0; e < 4; e++) {
                int q = tm * 128 + wm * 64 + mi * 16 + r4 * 4 + e;
                if (q < 900) {
                    float vv = acc[mi][ni][e] * inv + tbv;
                    vv = fminf(fmaxf(vv, -50000.f), 50000.f);
                    out[((size_t)b * 900 + q) * 1024 + l] = vv;
                }
            }
        }
    }
}

// ----------------------------------------------------------------
extern "C" void kernel_launch(void* const* d_in, const int* in_sizes, int n_in,
                              void* d_out, int out_size, void* d_ws, size_t ws_size,
                              hipStream_t stream)
{
    const float* x         = (const float*)d_in[0];
    const float* embedding = (const float*)d_in[1];
    const float* proj_w    = (const float*)d_in[2];
    const float* proj_b    = (const float*)d_in[3];
    const float* gate_w    = (const float*)d_in[4];
    const float* gate_b    = (const float*)d_in[5];
    const float* expert_w  = (const float*)d_in[6];
    const float* expert_b  = (const float*)d_in[7];
    const float* bias_lang = (const float*)d_in[8];
    const float* bias0     = (const float*)d_in[9];
    const float* log_scale = (const float*)d_in[10];
    float* out = (float*)d_out;

    size_t off = 0;
    char* base = (char*)d_ws;
    auto alloc = [&](size_t bytes) -> void* {
        void* p = base + off;
        off += (bytes + 255) & ~(size_t)255;
        return p;
    };
    unsigned short* emb_bf = (unsigned short*)alloc((size_t)65536 * 768 * 2); // 96MB
    unsigned short* x_bf   = (unsigned short*)alloc((size_t)14745600 * 2);    // 28MB
    unsigned short* wcatT  = (unsigned short*)alloc((size_t)2304 * 768 * 2);  // 3.4MB
    float* bcat            = (float*)alloc(2304 * 4);
    float* coef            = (float*)alloc((size_t)65536 * 16 * 4);           // 4MB
    float* tbias           = (float*)alloc((size_t)65536 * 4);
    unsigned short* tokens = (unsigned short*)alloc((size_t)65536 * 256 * 2); // 32MB

    k0_prep<<<57600, 256, 0, stream>>>(x, proj_w, proj_b, expert_w, expert_b,
                                       x_bf, wcatT, bcat);
    k1_gate<<<65536, 256, 0, stream>>>(embedding, gate_w, gate_b, bias_lang, bias0,
                                       emb_bf, coef, tbias);
    k2_tokens<<<512, 512, 0, stream>>>(emb_bf, wcatT, bcat, coef, tokens);
    dim3 g3(8, 8, 64);
    k3_logit<<<g3, 256, 0, stream>>>(x_bf, tokens, tbias, log_scale, out);
}

// Round 3
// 702.077 us; speedup vs baseline: 1.0754x; 1.0164x over previous
//
#include <hip/hip_runtime.h>
#include <hip/hip_bf16.h>

// BS=64 NQ=900 L=1024 D=768 H=256 E=8 TOPK=2 MOE_W=0.5
// out: (64,900,1024) f32
// Sparse MoE path: bucket rows by expert, gather-GEMM per expert (+proj),
// scatter scaled bf16 partials by slot, combine. 77 GF instead of dense 232 GF.

typedef __attribute__((ext_vector_type(8))) short bf16x8;
typedef __attribute__((ext_vector_type(4))) float f32x4;

#define NROW 65536            // 64*1024 token rows
#define CAP  65536            // per-expert bucket capacity (worst case)

__device__ __forceinline__ unsigned short f2bf(float f) {
    unsigned u = __builtin_bit_cast(unsigned, f);
    u += 0x7fffu + ((u >> 16) & 1u);   // RNE; inputs finite
    return (unsigned short)(u >> 16);
}
__device__ __forceinline__ float bf2f(unsigned short h) {
    unsigned u = ((unsigned)h) << 16;
    return __builtin_bit_cast(float, u);
}
__device__ __forceinline__ void gload16(const void* g, void* l) {
    __builtin_amdgcn_global_load_lds(
        (const __attribute__((address_space(1))) void*)g,
        (__attribute__((address_space(3))) void*)l, 16, 0, 0);
}

// ---------------------------------------------------------------- prep:
__global__ __launch_bounds__(256) void k0_prep(
    const float* __restrict__ x, const float* __restrict__ proj_w,
    const float* __restrict__ proj_b, const float* __restrict__ expert_w,
    const float* __restrict__ expert_b, unsigned short* __restrict__ x_bf,
    unsigned short* __restrict__ wcatT, float* __restrict__ bcat)
{
    int idx = blockIdx.x * 256 + threadIdx.x;
    if (idx < 64 * 900 * 256) x_bf[idx] = f2bf(x[idx]);
    if (idx < 2304 * 768) {
        int n = idx / 768, d = idx - n * 768;
        int j = n >> 8, h = n & 255;
        float v = (j < 8) ? expert_w[((size_t)j * 768 + d) * 256 + h]
                          : proj_w[(size_t)d * 256 + h];
        wcatT[(size_t)n * 768 + d] = f2bf(v);
    }
    if (idx < 2304) {
        int j = idx >> 8, h = idx & 255;
        bcat[idx] = (j < 8) ? expert_b[j * 256 + h] : proj_b[h];
    }
}

__global__ __launch_bounds__(64) void kz_zero(unsigned* __restrict__ cnt) {
    if (threadIdx.x < 8) cnt[threadIdx.x] = 0;
}

// ---------------------------------------------------------------- K1:
// normalize row, write emb bf16; gate softmax top-2 -> coef, top2 pack; token_bias.
__global__ __launch_bounds__(256) void k1_gate(
    const float* __restrict__ emb_in, const float* __restrict__ gate_w,
    const float* __restrict__ gate_b, const float* __restrict__ bias_lang,
    const float* __restrict__ bias0, unsigned short* __restrict__ emb_bf,
    float* __restrict__ coef, float* __restrict__ tbias,
    unsigned* __restrict__ top2)
{
    int r = blockIdx.x;
    int tid = threadIdx.x, lane = tid & 63, w = tid >> 6;
    const float* row = emb_in + (size_t)r * 768;
    float v0 = row[tid], v1 = row[tid + 256], v2 = row[tid + 512];
    float ss = v0 * v0 + v1 * v1 + v2 * v2;
    #pragma unroll
    for (int off = 32; off; off >>= 1) ss += __shfl_down(ss, off, 64);
    __shared__ float sred[4];
    __shared__ float srn;
    if (lane == 0) sred[w] = ss;
    __syncthreads();
    if (tid == 0) srn = rsqrtf(sred[0] + sred[1] + sred[2] + sred[3]);
    __syncthreads();
    float rn = srn;
    float e0 = v0 * rn, e1 = v1 * rn, e2 = v2 * rn;
    emb_bf[(size_t)r * 768 + tid]       = f2bf(e0);
    emb_bf[(size_t)r * 768 + tid + 256] = f2bf(e1);
    emb_bf[(size_t)r * 768 + tid + 512] = f2bf(e2);

    float red[9];
    #pragma unroll
    for (int i = 0; i < 9; i++) red[i] = 0.f;
    float ev[3] = {e0, e1, e2};
    #pragma unroll
    for (int k = 0; k < 3; k++) {
        int d = tid + 256 * k;
        float ed = ev[k];
        #pragma unroll
        for (int e = 0; e < 8; e++) red[e] += ed * gate_w[d * 8 + e];
        red[8] += ed * bias_lang[d];
    }
    #pragma unroll
    for (int off = 32; off; off >>= 1) {
        #pragma unroll
        for (int i = 0; i < 9; i++) red[i] += __shfl_down(red[i], off, 64);
    }
    __shared__ float sg[4][9];
    if (lane == 0) {
        #pragma unroll
        for (int i = 0; i < 9; i++) sg[w][i] = red[i];
    }
    __syncthreads();
    if (tid == 0) {
        float g[8];
        #pragma unroll
        for (int e = 0; e < 8; e++)
            g[e] = sg[0][e] + sg[1][e] + sg[2][e] + sg[3][e] + gate_b[e];
        float tb = sg[0][8] + sg[1][8] + sg[2][8] + sg[3][8] + bias0[0];
        float m = g[0];
        #pragma unroll
        for (int e = 1; e < 8; e++) m = fmaxf(m, g[e]);
        float p[8], s = 0.f;
        #pragma unroll
        for (int e = 0; e < 8; e++) { p[e] = __expf(g[e] - m); s += p[e]; }
        float inv = 1.f / s;
        int i1 = 0;
        #pragma unroll
        for (int e = 1; e < 8; e++) if (g[e] > g[i1]) i1 = e;
        int i2 = (i1 == 0) ? 1 : 0;
        #pragma unroll
        for (int e = 0; e < 8; e++) if (e != i1 && g[e] > g[i2]) i2 = e;
        float cc[9];
        #pragma unroll
        for (int j = 0; j < 9; j++) cc[j] = 0.f;
        cc[i1] = 0.5f * p[i1] * inv;
        cc[i2] = 0.5f * p[i2] * inv;
        cc[8]  = 0.5f;
        #pragma unroll
        for (int j = 0; j < 9; j++) coef[(size_t)r * 16 + j] = cc[j];
        tbias[r] = tb;
        top2[r] = (unsigned)i1 | ((unsigned)i2 << 8);
    }
}

// ---------------------------------------------------------------- KB:
// wave-aggregated bucketing: one atomic per (wave, expert, slot) with ballot.
__global__ __launch_bounds__(256) void kb_bucket(
    const unsigned* __restrict__ top2, const float* __restrict__ coef,
    unsigned* __restrict__ cnt, unsigned* __restrict__ bidx,
    float* __restrict__ bscale)
{
    int r = blockIdx.x * 256 + threadIdx.x;     // NROW exact multiple
    int lane = threadIdx.x & 63;
    unsigned t = top2[r];
    int ii[2] = { (int)(t & 255), (int)((t >> 8) & 255) };
    #pragma unroll
    for (int slot = 0; slot < 2; slot++) {
        int myE = ii[slot];
        float c = coef[(size_t)r * 16 + myE];
        #pragma unroll 1
        for (int e = 0; e < 8; e++) {
            unsigned long long mask = __ballot(myE == e);
            if (myE == e) {
                int leader = __ffsll((unsigned long long)mask) - 1;
                unsigned base = 0;
                if (lane == leader)
                    base = atomicAdd(&cnt[e], (unsigned)__popcll(mask));
                base = __shfl(base, leader, 64);
                unsigned pos = base + (unsigned)__popcll(mask & ((1ull << lane) - 1ull));
                bidx[(size_t)e * CAP + pos]   = (unsigned)r | ((unsigned)slot << 16);
                bscale[(size_t)e * CAP + pos] = c;
            }
        }
    }
}

// ---------------------------------------------------------------- K2E:
// gather-GEMM: partial[slot][row] = scale * (emb[row] @ W_j + b_j).
// grid (tile, j): j<8 = expert bucket (gathered rows), j=8 = proj (identity, 0.5).
// BM=128 BN=256 BK=32, 8 waves (2Mx4N, 64x64 each), 2-phase dbuf, seg-swizzle.
__global__ __launch_bounds__(512, 2) void k2_expert(
    const unsigned short* __restrict__ emb_bf, const unsigned short* __restrict__ wcatT,
    const float* __restrict__ bcat, const unsigned* __restrict__ cnt,
    const unsigned* __restrict__ bidx, const float* __restrict__ bscale,
    unsigned short* __restrict__ partial)
{
    int e = blockIdx.y;                 // 0..8, 8 = proj
    int tile = blockIdx.x;
    int cnt_e = (e < 8) ? (int)cnt[e] : NROW;
    if (tile * 128 >= cnt_e) return;
    int tid = threadIdx.x, lane = tid & 63, w = tid >> 6;
    int wm = w >> 2, wn = w & 3;
    __shared__ __align__(16) unsigned short As[2][128 * 32];   // 2 x 8KB
    __shared__ __align__(16) unsigned short Bs[2][256 * 32];   // 2 x 16KB
    __shared__ unsigned sRow[128];
    __shared__ float sScale[128];
    if (tid < 128) {
        int gi = tile * 128 + tid;
        unsigned rs; float sc;
        if (e == 8)           { rs = (unsigned)gi | (2u << 16); sc = 0.5f; }
        else if (gi < cnt_e)  { rs = bidx[(size_t)e * CAP + gi];
                                sc = bscale[(size_t)e * CAP + gi]; }
        else                  { rs = 0; sc = 0.f; }   // clamp; stores guarded
        sRow[tid] = rs; sScale[tid] = sc;
    }
    __syncthreads();
    int r16 = lane & 15, r4 = lane >> 4;
    int srowA = tid >> 2, ssegA = (tid & 3) ^ (srowA & 3);
    const unsigned short* aSrc =
        emb_bf + (size_t)(sRow[srowA] & 0xFFFFu) * 768 + ssegA * 8;
    const unsigned short* bBase = wcatT + (size_t)e * 256 * 768;

    auto stageA = [&](int kt, int buf) {
        gload16(aSrc + kt * 32, &As[buf][w * 512]);
    };
    auto stageB = [&](int kt, int buf) {
        #pragma unroll
        for (int i = 0; i < 2; i++) {
            int u = i * 512 + tid;
            int brow = u >> 2, seg = (u & 3) ^ (brow & 3);
            gload16(&bBase[(size_t)brow * 768 + kt * 32 + seg * 8],
                    &Bs[buf][i * 4096 + w * 512]);
        }
    };

    f32x4 acc[4][4];
    #pragma unroll
    for (int mi = 0; mi < 4; mi++)
        #pragma unroll
        for (int ni = 0; ni < 4; ni++) acc[mi][ni] = f32x4{0.f, 0.f, 0.f, 0.f};

    stageA(0, 0); stageB(0, 0);
    __syncthreads();
    int buf = 0;
    #pragma unroll 1
    for (int kt = 0; kt < 24; ++kt) {
        if (kt < 23) { stageA(kt + 1, buf ^ 1); stageB(kt + 1, buf ^ 1); }
        bf16x8 a[4], b[4];
        #pragma unroll
        for (int mi = 0; mi < 4; mi++) {
            int arow = wm * 64 + mi * 16 + r16;
            a[mi] = *(const bf16x8*)&As[buf][arow * 32 + (r4 ^ (arow & 3)) * 8];
        }
        #pragma unroll
        for (int ni = 0; ni < 4; ni++) {
            int brow = wn * 64 + ni * 16 + r16;
            b[ni] = *(const bf16x8*)&Bs[buf][brow * 32 + (r4 ^ (brow & 3)) * 8];
        }
        #pragma unroll
        for (int mi = 0; mi < 4; mi++)
            #pragma unroll
            for (int ni = 0; ni < 4; ni++)
                acc[mi][ni] = __builtin_amdgcn_mfma_f32_16x16x32_bf16(
                    a[mi], b[ni], acc[mi][ni], 0, 0, 0);
        __syncthreads();
        buf ^= 1;
    }

    float bj[4];
    #pragma unroll
    for (int ni = 0; ni < 4; ni++) bj[ni] = bcat[e * 256 + wn * 64 + ni * 16 + r16];
    #pragma unroll
    for (int mi = 0; mi < 4; mi++) {
        #pragma unroll
        for (int e4 = 0; e4 < 4; e4++) {
            int rl = wm * 64 + mi * 16 + r4 * 4 + e4;
            if (tile * 128 + rl < cnt_e) {
                unsigned rs = sRow[rl];
                float sc = sScale[rl];
                unsigned rowg = rs & 0xFFFFu, slot = rs >> 16;
                #pragma unroll
                for (int ni = 0; ni < 4; ni++) {
                    int col = wn * 64 + ni * 16 + r16;
                    partial[((size_t)slot * NROW + rowg) * 256 + col] =
                        f2bf(sc * (acc[mi][ni][e4] + bj[ni]));
                }
            }
        }
    }
}

// ---------------------------------------------------------------- K2C:
// tokens = bf16( partial0 + partial1 + partial2 )
__global__ __launch_bounds__(256) void k2_combine(
    const unsigned short* __restrict__ partial, unsigned short* __restrict__ tokens)
{
    size_t i = ((size_t)blockIdx.x * 256 + threadIdx.x) * 8;
    const size_t S = (size_t)NROW * 256;
    bf16x8 p0 = *(const bf16x8*)&partial[i];
    bf16x8 p1 = *(const bf16x8*)&partial[S + i];
    bf16x8 p2 = *(const bf16x8*)&partial[2 * S + i];
    union { bf16x8 v; unsigned short s[8]; } o;
    #pragma unroll
    for (int e = 0; e < 8; e++)
        o.s[e] = f2bf(bf2f((unsigned short)p0[e]) + bf2f((unsigned short)p1[e]) +
                      bf2f((unsigned short)p2[e]));
    *(bf16x8*)&tokens[i] = o.v;
}

// ---------------------------------------------------------------- K3:
__global__ __launch_bounds__(256, 3) void k3_logit(
    const unsigned short* __restrict__ x_bf, const unsigned short* __restrict__ tokens,
    const float* __restrict__ tbias, const float* __restrict__ log_scale,
    float* __restrict__ out)
{
    int tid = threadIdx.x, lane = tid & 63, w = tid >> 6;
    int wm = w >> 1, wn = w & 1;
    int tn = blockIdx.x, tm = blockIdx.y, b = blockIdx.z;
    __shared__ __align__(16) unsigned short As[2][128 * 32];
    __shared__ __align__(16) unsigned short Bs[2][128 * 32];
    const unsigned short* A = x_bf + (size_t)b * 900 * 256;
    const unsigned short* B = tokens + (size_t)b * 1024 * 256;
    f32x4 acc[4][4];
    #pragma unroll
    for (int mi = 0; mi < 4; mi++)
        #pragma unroll
        for (int ni = 0; ni < 4; ni++) acc[mi][ni] = f32x4{0.f, 0.f, 0.f, 0.f};
    int r16 = lane & 15, r4 = lane >> 4;

    auto stage = [&](int kt, int buf) {
        #pragma unroll
        for (int i = 0; i < 2; i++) {
            int u = i * 256 + tid;
            int row = u >> 2, seg = (u & 3) ^ (row & 3);
            int ar = tm * 128 + row;
            if (ar > 899) ar = 899;
            gload16(&A[(size_t)ar * 256 + kt * 32 + seg * 8],
                    &As[buf][i * 2048 + w * 512]);
            int nr = tn * 128 + row;
            gload16(&B[(size_t)nr * 256 + kt * 32 + seg * 8],
                    &Bs[buf][i * 2048 + w * 512]);
        }
    };

    stage(0, 0);
    __syncthreads();
    int buf = 0;
    #pragma unroll 1
    for (int kt = 0; kt < 8; ++kt) {
        if (kt < 7) stage(kt + 1, buf ^ 1);
        bf16x8 a[4], bb[4];
        #pragma unroll
        for (int mi = 0; mi < 4; mi++) {
            int row = wm * 64 + mi * 16 + r16;
            a[mi] = *(const bf16x8*)&As[buf][row * 32 + (r4 ^ (row & 3)) * 8];
        }
        #pragma unroll
        for (int ni = 0; ni < 4; ni++) {
            int row = wn * 64 + ni * 16 + r16;
            bb[ni] = *(const bf16x8*)&Bs[buf][row * 32 + (r4 ^ (row & 3)) * 8];
        }
        #pragma unroll
        for (int mi = 0; mi < 4; mi++)
            #pragma unroll
            for (int ni = 0; ni < 4; ni++)
                acc[mi][ni] = __builtin_amdgcn_mfma_f32_16x16x32_bf16(
                    a[mi], bb[ni], acc[mi][ni], 0, 0, 0);
        __syncthreads();
        buf ^= 1;
    }
    float inv = __expf(-log_scale[0]);
    #pragma unroll
    for (int ni = 0; ni < 4; ni++) {
        int l = tn * 128 + wn * 64 + ni * 16 + r16;
        float tbv = tbias[b * 1024 + l];
        #pragma unroll
        for (int mi = 0; mi < 4; mi++) {
            #pragma unroll
            for (int e = 0; e < 4; e++) {
                int q = tm * 128 + wm * 64 + mi * 16 + r4 * 4 + e;
                if (q < 900) {
                    float vv = acc[mi][ni][e] * inv + tbv;
                    vv = fminf(fmaxf(vv, -50000.f), 50000.f);
                    out[((size_t)b * 900 + q) * 1024 + l] = vv;
                }
            }
        }
    }
}

// ----------------------------------------------------------------
extern "C" void kernel_launch(void* const* d_in, const int* in_sizes, int n_in,
                              void* d_out, int out_size, void* d_ws, size_t ws_size,
                              hipStream_t stream)
{
    const float* x         = (const float*)d_in[0];
    const float* embedding = (const float*)d_in[1];
    const float* proj_w    = (const float*)d_in[2];
    const float* proj_b    = (const float*)d_in[3];
    const float* gate_w    = (const float*)d_in[4];
    const float* gate_b    = (const float*)d_in[5];
    const float* expert_w  = (const float*)d_in[6];
    const float* expert_b  = (const float*)d_in[7];
    const float* bias_lang = (const float*)d_in[8];
    const float* bias0     = (const float*)d_in[9];
    const float* log_scale = (const float*)d_in[10];
    float* out = (float*)d_out;

    size_t off = 0;
    char* base = (char*)d_ws;
    auto alloc = [&](size_t bytes) -> void* {
        void* p = base + off;
        off += (bytes + 255) & ~(size_t)255;
        return p;
    };
    unsigned short* emb_bf  = (unsigned short*)alloc((size_t)NROW * 768 * 2);     // 96MB
    unsigned short* x_bf    = (unsigned short*)alloc((size_t)14745600 * 2);       // 28MB
    unsigned short* wcatT   = (unsigned short*)alloc((size_t)2304 * 768 * 2);     // 3.4MB
    float* bcat             = (float*)alloc(2304 * 4);
    float* coef             = (float*)alloc((size_t)NROW * 16 * 4);               // 4MB
    float* tbias            = (float*)alloc((size_t)NROW * 4);
    unsigned short* tokens  = (unsigned short*)alloc((size_t)NROW * 256 * 2);     // 32MB
    unsigned* cnt           = (unsigned*)alloc(8 * 4);
    unsigned* top2          = (unsigned*)alloc((size_t)NROW * 4);                 // 256KB
    unsigned* bidx          = (unsigned*)alloc((size_t)8 * CAP * 4);              // 2MB
    float* bscale           = (float*)alloc((size_t)8 * CAP * 4);                 // 2MB
    unsigned short* partial = (unsigned short*)alloc((size_t)3 * NROW * 256 * 2); // 96MB

    k0_prep<<<57600, 256, 0, stream>>>(x, proj_w, proj_b, expert_w, expert_b,
                                       x_bf, wcatT, bcat);
    kz_zero<<<1, 64, 0, stream>>>(cnt);
    k1_gate<<<NROW, 256, 0, stream>>>(embedding, gate_w, gate_b, bias_lang, bias0,
                                      emb_bf, coef, tbias, top2);
    kb_bucket<<<NROW / 256, 256, 0, stream>>>(top2, coef, cnt, bidx, bscale);
    dim3 g2(512, 9);
    k2_expert<<<g2, 512, 0, stream>>>(emb_bf, wcatT, bcat, cnt, bidx, bscale, partial);
    k2_combine<<<8192, 256, 0, stream>>>(partial, tokens);
    dim3 g3(8, 8, 64);
    k3_logit<<<g3, 256, 0, stream>>>(x_bf, tokens, tbias, log_scale, out);
}